// Round 5
// baseline (702.990 us; speedup 1.0000x reference)
//
#include <hip/hip_runtime.h>
#include <hip/hip_bf16.h>

#define IN_CH 128
#define OUT_CH 128
#define LDSPAD 136   // padded row stride (elements); 16B-aligned fragment reads, 2-way
                     // bank aliasing only (free per m136)

typedef short bf16x8 __attribute__((ext_vector_type(8)));
typedef float f32x4  __attribute__((ext_vector_type(4)));

__device__ __forceinline__ unsigned short f32_to_bf16_bits(float f) {
    unsigned u = __builtin_bit_cast(unsigned, f);
    u += 0x7FFFu + ((u >> 16) & 1u);   // RNE; finite values only in this pipeline
    return (unsigned short)(u >> 16);
}
__device__ __forceinline__ float bf16_bits_to_f32(unsigned short b) {
    return __builtin_bit_cast(float, (unsigned)b << 16);
}

// ---------------------------------------------------------------------------
// Kernel 0: runtime dtype detection (1 block). flags[0]=X fp32, flags[1]=W1 fp32,
// flags[2]=W2 fp32, flags[3]=idx int64
// ---------------------------------------------------------------------------
__global__ void detect_kernel(const unsigned short* __restrict__ X,
                              const unsigned short* __restrict__ W1,
                              const unsigned short* __restrict__ W2,
                              const int* __restrict__ idx,
                              int* __restrict__ flags) {
    __shared__ int red[4];
    const int t = threadIdx.x;
    if (t < 4) red[t] = 0;
    __syncthreads();
    #pragma unroll
    for (int w = 0; w < 3; ++w) {
        const unsigned short* p = (w == 0) ? X : (w == 1) ? W1 : W2;
        int crazy = 0;
        for (int j = t; j < 512; j += 256) {
            const unsigned short h = p[j];
            const int e = (h >> 7) & 0xFF;
            const int man = h & 0x7F;
            // insane as bf16 for this data: |v| >= 2^17, or denormal
            if (e >= 0x90 || (e == 0 && man != 0)) crazy++;
        }
        if (crazy) atomicAdd(&red[w], crazy);
    }
    {   // idx: odd int32 words are int64 high-words (all 0 since values < 10000)
        if (idx[2 * t + 1] != 0) atomicAdd(&red[3], 1);
    }
    __syncthreads();
    if (t == 0) {
        flags[0] = red[0] > 16 ? 1 : 0;
        flags[1] = red[1] > 16 ? 1 : 0;
        flags[2] = red[2] > 16 ? 1 : 0;
        flags[3] = red[3] < 8  ? 1 : 0;
    }
}

// ---------------------------------------------------------------------------
// Kernel 1: per-segment counts (idx-width adaptive)
// ---------------------------------------------------------------------------
__global__ void count_kernel(const int* __restrict__ idx, int* __restrict__ cnt,
                             const int* __restrict__ flags, int n) {
    const int sh = flags[3];
    int i = blockIdx.x * blockDim.x + threadIdx.x;
    if (i < n) atomicAdd(&cnt[idx[(size_t)i << sh]], 1);
}

// ---------------------------------------------------------------------------
// Kernel 2: fused MLP (2x Linear+ReLU via MFMA) + fp32 atomic scatter.
// Block = 256 threads = 4 waves; 16-row X tile per iteration; wave w owns
// output channels [32w,32w+32) as two 16x16 n-tiles.
// ---------------------------------------------------------------------------
__global__ __launch_bounds__(256)
void mlp_scatter_kernel(const unsigned short* __restrict__ X,
                        const int* __restrict__ idx,
                        const unsigned short* __restrict__ W1,
                        const unsigned short* __restrict__ B1,
                        const unsigned short* __restrict__ W2,
                        const unsigned short* __restrict__ B2,
                        float* __restrict__ seg_sum,
                        const int* __restrict__ flags,
                        int n_src, int n_tiles)
{
    __shared__ short lds_x[16 * LDSPAD];
    __shared__ short lds_h[16 * LDSPAD];

    const int xf32  = flags[0];
    const int w1f32 = flags[1];
    const int w2f32 = flags[2];
    const int i64   = flags[3];

    const int tid  = threadIdx.x;
    const int wave = tid >> 6;
    const int lane = tid & 63;
    const int m    = lane & 15;   // A row / B col / D col
    const int quad = lane >> 4;

    // Preload this wave's W1/W2 B-fragments (B[k][n]=W[n][k] -> 8 contiguous k
    // from row n of row-major W) and biases.
    bf16x8 w1f[2][4], w2f[2][4];
    float  b1c[2], b2c[2];
    #pragma unroll
    for (int t = 0; t < 2; ++t) {
        const int n = wave * 32 + t * 16 + m;
        b1c[t] = w1f32 ? ((const float*)B1)[n] : bf16_bits_to_f32(B1[n]);
        b2c[t] = w2f32 ? ((const float*)B2)[n] : bf16_bits_to_f32(B2[n]);
        #pragma unroll
        for (int kc = 0; kc < 4; ++kc) {
            const int ko = kc * 32 + quad * 8;
            if (w1f32) {
                const float* Wf = (const float*)W1;
                f32x4 lo = *(const f32x4*)(Wf + n * IN_CH + ko);
                f32x4 hi = *(const f32x4*)(Wf + n * IN_CH + ko + 4);
                bf16x8 v;
                #pragma unroll
                for (int j = 0; j < 4; ++j) {
                    v[j]     = (short)f32_to_bf16_bits(lo[j]);
                    v[4 + j] = (short)f32_to_bf16_bits(hi[j]);
                }
                w1f[t][kc] = v;
            } else {
                w1f[t][kc] = *(const bf16x8*)(W1 + n * IN_CH + ko);
            }
            if (w2f32) {
                const float* Wf = (const float*)W2;
                f32x4 lo = *(const f32x4*)(Wf + n * OUT_CH + ko);
                f32x4 hi = *(const f32x4*)(Wf + n * OUT_CH + ko + 4);
                bf16x8 v;
                #pragma unroll
                for (int j = 0; j < 4; ++j) {
                    v[j]     = (short)f32_to_bf16_bits(lo[j]);
                    v[4 + j] = (short)f32_to_bf16_bits(hi[j]);
                }
                w2f[t][kc] = v;
            } else {
                w2f[t][kc] = *(const bf16x8*)(W2 + n * OUT_CH + ko);
            }
        }
    }

    const int srow = tid >> 4;   // staging: 16 threads/row
    const int sseg = tid & 15;

    for (int tile = blockIdx.x; tile < n_tiles; tile += gridDim.x) {
        const int r0 = tile * 16;

        // ---- stage X tile into padded LDS (dtype-adaptive) ----
        {
            const int gr = r0 + srow;
            bf16x8 v = {0, 0, 0, 0, 0, 0, 0, 0};
            if (gr < n_src) {
                if (xf32) {
                    const float* Xf = (const float*)X;
                    f32x4 lo = *(const f32x4*)(Xf + (size_t)gr * IN_CH + sseg * 8);
                    f32x4 hi = *(const f32x4*)(Xf + (size_t)gr * IN_CH + sseg * 8 + 4);
                    #pragma unroll
                    for (int j = 0; j < 4; ++j) {
                        v[j]     = (short)f32_to_bf16_bits(lo[j]);
                        v[4 + j] = (short)f32_to_bf16_bits(hi[j]);
                    }
                } else {
                    v = *(const bf16x8*)(X + (size_t)gr * IN_CH + sseg * 8);
                }
            }
            *(bf16x8*)&lds_x[srow * LDSPAD + sseg * 8] = v;
        }
        __syncthreads();

        // ---- layer 1 ----
        f32x4 acc0 = {0.f, 0.f, 0.f, 0.f}, acc1 = {0.f, 0.f, 0.f, 0.f};
        #pragma unroll
        for (int kc = 0; kc < 4; ++kc) {
            bf16x8 a = *(const bf16x8*)&lds_x[m * LDSPAD + kc * 32 + quad * 8];
            acc0 = __builtin_amdgcn_mfma_f32_16x16x32_bf16(a, w1f[0][kc], acc0, 0, 0, 0);
            acc1 = __builtin_amdgcn_mfma_f32_16x16x32_bf16(a, w1f[1][kc], acc1, 0, 0, 0);
        }
        // relu+bias; D (col=lane&15,row=quad*4+reg) -> lds_h[src_row][channel]
        #pragma unroll
        for (int t = 0; t < 2; ++t) {
            const int col = wave * 32 + t * 16 + m;
            const float bias = b1c[t];
            const f32x4 acc = t == 0 ? acc0 : acc1;
            #pragma unroll
            for (int r = 0; r < 4; ++r) {
                float v = acc[r] + bias;
                v = v > 0.f ? v : 0.f;
                lds_h[(quad * 4 + r) * LDSPAD + col] = (short)f32_to_bf16_bits(v);
            }
        }
        __syncthreads();

        // ---- layer 2 ----
        f32x4 acc2_0 = {0.f, 0.f, 0.f, 0.f}, acc2_1 = {0.f, 0.f, 0.f, 0.f};
        #pragma unroll
        for (int kc = 0; kc < 4; ++kc) {
            bf16x8 a = *(const bf16x8*)&lds_h[m * LDSPAD + kc * 32 + quad * 8];
            acc2_0 = __builtin_amdgcn_mfma_f32_16x16x32_bf16(a, w2f[0][kc], acc2_0, 0, 0, 0);
            acc2_1 = __builtin_amdgcn_mfma_f32_16x16x32_bf16(a, w2f[1][kc], acc2_1, 0, 0, 0);
        }

        // ---- relu+bias + fp32 atomic scatter ----
        int seg[4];
        #pragma unroll
        for (int r = 0; r < 4; ++r) {
            const int grow = r0 + quad * 4 + r;
            seg[r] = (grow < n_src) ? idx[(size_t)grow << i64] : -1;
        }
        #pragma unroll
        for (int t = 0; t < 2; ++t) {
            const int col = wave * 32 + t * 16 + m;
            const float bias = b2c[t];
            const f32x4 acc = t == 0 ? acc2_0 : acc2_1;
            #pragma unroll
            for (int r = 0; r < 4; ++r) {
                if (seg[r] >= 0) {
                    float v = acc[r] + bias;
                    v = v > 0.f ? v : 0.f;
                    unsafeAtomicAdd(&seg_sum[(size_t)seg[r] * OUT_CH + col], v);
                }
            }
        }
    }
}

// ---------------------------------------------------------------------------
// Kernel 3: divide by count. OUTPUT IS FP32 (reference promotes bf16@fp32 ->
// fp32; R2/R3/R4's bit-identical half-buffer-zero signature).
// ---------------------------------------------------------------------------
__global__ void finalize_kernel(const float* __restrict__ seg_sum,
                                const int* __restrict__ cnt,
                                float* __restrict__ out, int total) {
    int i = blockIdx.x * blockDim.x + threadIdx.x;
    if (i < total) {
        int c = cnt[i >> 7];           // OUT_CH = 128
        c = c > 1 ? c : 1;
        out[i] = seg_sum[i] / (float)c;
    }
}

extern "C" void kernel_launch(void* const* d_in, const int* in_sizes, int n_in,
                              void* d_out, int out_size, void* d_ws, size_t ws_size,
                              hipStream_t stream) {
    // size-based input resolution (proven equivalent to ordered mapping in R3)
    int iX = 0;
    for (int i = 1; i < n_in; ++i)
        if (in_sizes[i] > in_sizes[iX]) iX = i;
    const int n_src = in_sizes[iX] / IN_CH;
    int iI = -1, iW1 = -1, iW2 = -1, iB1 = -1, iB2 = -1;
    for (int i = 0; i < n_in; ++i) {
        if (i == iX) continue;
        const int s = in_sizes[i];
        if (s == n_src && iI < 0) iI = i;
        else if (s == IN_CH * OUT_CH) { if (iW1 < 0) iW1 = i; else if (iW2 < 0) iW2 = i; }
        else if (s == OUT_CH) { if (iB1 < 0) iB1 = i; else if (iB2 < 0) iB2 = i; }
    }

    const unsigned short* X  = (const unsigned short*)d_in[iX];
    const int*            ix = (const int*)d_in[iI];
    const unsigned short* W1 = (const unsigned short*)d_in[iW1];
    const unsigned short* B1 = (const unsigned short*)d_in[iB1];
    const unsigned short* W2 = (const unsigned short*)d_in[iW2];
    const unsigned short* B2 = (const unsigned short*)d_in[iB2];
    float* out = (float*)d_out;

    const int dim = out_size / OUT_CH;

    int*   flags   = (int*)d_ws;                                   // [0,256) reserved
    float* seg_sum = (float*)((char*)d_ws + 256);
    int*   cnt     = (int*)((char*)d_ws + 256 + (size_t)dim * OUT_CH * sizeof(float));

    hipMemsetAsync((char*)d_ws + 256, 0,
                   (size_t)dim * OUT_CH * sizeof(float) + (size_t)dim * sizeof(int),
                   stream);

    detect_kernel<<<1, 256, 0, stream>>>(X, W1, W2, ix, flags);

    count_kernel<<<(n_src + 255) / 256, 256, 0, stream>>>(ix, cnt, flags, n_src);

    const int n_tiles = (n_src + 15) / 16;
    const int grid = n_tiles < 10000 ? n_tiles : 10000;
    mlp_scatter_kernel<<<grid, 256, 0, stream>>>(X, ix, W1, B1, W2, B2, seg_sum,
                                                 flags, n_src, n_tiles);

    finalize_kernel<<<(out_size + 255) / 256, 256, 0, stream>>>(seg_sum, cnt, out, out_size);
}